// Round 3
// baseline (3682.446 us; speedup 1.0000x reference)
//
#include <hip/hip_runtime.h>
#include <hip/hip_fp16.h>
#include <math.h>

#define N_NODES 100000
#define N_EDGES 1000000
#define F_IN    128
#define HID     64
#define HEADS   4
#define NCLS    4

// ---------------- helpers ----------------
__device__ __forceinline__ float wsum(float v) {
#pragma unroll
  for (int o = 32; o > 0; o >>= 1) v += __shfl_xor(v, o, 64);
  return v;
}
// monotonic float<->signed-int order mapping (for atomicMax on float scores)
__device__ __forceinline__ int f2ord(float f) {
  int b = __float_as_int(f);
  return b >= 0 ? b : (b ^ 0x7FFFFFFF);
}
__device__ __forceinline__ float ord2f(int k) {
  return __int_as_float(k >= 0 ? k : (k ^ 0x7FFFFFFF));
}
__device__ __forceinline__ void atomAdd(float* p, float v) {
  unsafeAtomicAdd(p, v);  // native global_atomic_add_f32 on gfx950
}

// ---------------- dense: xw = x@gcn_W ; xp = x@proj_W + proj_b ----------------
__global__ __launch_bounds__(128) void k_in_gemm(
    const float* __restrict__ x, const float* __restrict__ gcn_W,
    const float* __restrict__ proj_W, const float* __restrict__ proj_b,
    float* __restrict__ xw, float* __restrict__ xp) {
  int f = threadIdx.x & 63;
  bool is_proj = threadIdx.x >= 64;
  const float* W = is_proj ? proj_W : gcn_W;
  int n0 = blockIdx.x * 8;
  float acc[8] = {0.f,0.f,0.f,0.f,0.f,0.f,0.f,0.f};
  for (int k = 0; k < F_IN; ++k) {
    float w = W[k * HID + f];
#pragma unroll
    for (int j = 0; j < 8; ++j) acc[j] += x[(size_t)(n0 + j) * F_IN + k] * w;
  }
  if (is_proj) {
    float b = proj_b[f];
#pragma unroll
    for (int j = 0; j < 8; ++j) xp[(size_t)(n0 + j) * HID + f] = acc[j] + b;
  } else {
#pragma unroll
    for (int j = 0; j < 8; ++j) xw[(size_t)(n0 + j) * HID + f] = acc[j];
  }
}

// ---------------- GCN degree ----------------
__global__ void k_deg_init(float* __restrict__ deg) {
  int i = blockIdx.x * 256 + threadIdx.x;
  if (i < N_NODES) deg[i] = 1.0f;  // self-loop weight
}
__global__ void k_deg_scatter(const int* __restrict__ dst, const float* __restrict__ w,
                              float* __restrict__ deg) {
  int e = blockIdx.x * 256 + threadIdx.x;
  if (e < N_EDGES) atomAdd(&deg[dst[e]], w[e]);
}
// dinv + self-loop init of the GCN accumulator: acc[i] = dinv[i]^2 * xw[i]
__global__ void k_gcn_self(const float* __restrict__ deg, const float* __restrict__ xw,
                           float* __restrict__ dinv, float* __restrict__ acc) {
  int idx = blockIdx.x * 256 + threadIdx.x;  // N*64 exact
  int i = idx >> 6, c = idx & 63;
  float d = deg[i];
  float di = d > 0.f ? rsqrtf(d) : 0.f;
  if (c == 0) dinv[i] = di;
  acc[idx] = di * di * xw[idx];
}
// edge scatter: 16 threads/edge, float4 each
__global__ void k_gcn_scatter(const int* __restrict__ src, const int* __restrict__ dst,
                              const float* __restrict__ w, const float* __restrict__ dinv,
                              const float* __restrict__ xw, float* __restrict__ acc) {
  int idx = blockIdx.x * 256 + threadIdx.x;
  int e = idx >> 4, q = idx & 15;
  if (e >= N_EDGES) return;
  int s = src[e], d = dst[e];
  float nrm = dinv[s] * w[e] * dinv[d];
  float4 v = reinterpret_cast<const float4*>(xw + (size_t)s * HID)[q];
  float* p = acc + (size_t)d * HID + q * 4;
  atomAdd(p + 0, nrm * v.x);
  atomAdd(p + 1, nrm * v.y);
  atomAdd(p + 2, nrm * v.z);
  atomAdd(p + 3, nrm * v.w);
}

// ---------------- generic out = relu(LN(acc+bias; g,b)) + add ----------------
__global__ __launch_bounds__(256) void k_ln_relu_add(
    const float* __restrict__ acc, const float* __restrict__ bias,
    const float* __restrict__ g, const float* __restrict__ b,
    const float* __restrict__ add, float* __restrict__ out) {
  int n = blockIdx.x * 4 + (threadIdx.x >> 6);
  int lane = threadIdx.x & 63;
  size_t base = (size_t)n * HID;
  float v = acc[base + lane] + bias[lane];
  float mu = wsum(v) * (1.f / HID);
  float dv = v - mu;
  float var = wsum(dv * dv) * (1.f / HID);
  float h = dv * rsqrtf(var + 1e-5f) * g[lane] + b[lane];
  h = h > 0.f ? h : 0.f;
  out[base + lane] = h + add[base + lane];
}

// ---------------- GATv2 linear: xl = h@Wl, xr = h@Wr (fp16 out, each [N,256]) ----
__global__ __launch_bounds__(512) void k_gat_gemm(
    const float* __restrict__ h, const float* __restrict__ Wl,
    const float* __restrict__ Wr, __half* __restrict__ xl, __half* __restrict__ xr) {
  int f = threadIdx.x & 255;
  bool right = threadIdx.x >= 256;
  const float* W = right ? Wr : Wl;
  __half* out = right ? xr : xl;
  int n0 = blockIdx.x * 8;
  float acc[8] = {0.f,0.f,0.f,0.f,0.f,0.f,0.f,0.f};
  for (int k = 0; k < HID; ++k) {
    float w = W[k * 256 + f];
#pragma unroll
    for (int j = 0; j < 8; ++j) acc[j] += h[(size_t)(n0 + j) * HID + k] * w;
  }
#pragma unroll
  for (int j = 0; j < 8; ++j) out[(size_t)(n0 + j) * 256 + f] = __float2half(acc[j]);
}

__global__ void k_gat_init(float* __restrict__ gat_acc, int* __restrict__ smax_i,
                           float* __restrict__ den) {
  int idx = blockIdx.x * 256 + threadIdx.x;  // N*64 exact
  gat_acc[idx] = 0.f;
  int i = idx >> 6, c = idx & 63;
  if (c < 4) { smax_i[i * 4 + c] = (int)0x80000000; den[i * 4 + c] = 0.f; }
}

struct Half4 { __half2 a, b; };
__device__ __forceinline__ float4 ld_half4(const __half* p) {
  Half4 h = *reinterpret_cast<const Half4*>(p);
  float2 f0 = __half22float2(h.a), f1 = __half22float2(h.b);
  return make_float4(f0.x, f0.y, f1.x, f1.y);
}

// pass A: per-edge scores (one wave per edge; lane holds 4 of 256 elems, all in one head)
__global__ __launch_bounds__(256) void k_gat_score(
    const __half* __restrict__ xl, const __half* __restrict__ xr,
    const int* __restrict__ src, const int* __restrict__ dst,
    const float* __restrict__ att, float* __restrict__ score, int* __restrict__ smax_i) {
  int e = blockIdx.x * 4 + (threadIdx.x >> 6);
  if (e >= N_EDGES + N_NODES) return;
  int lane = threadIdx.x & 63;
  int s, d;
  if (e < N_EDGES) { s = src[e]; d = dst[e]; } else { s = e - N_EDGES; d = s; }
  float4 a = ld_half4(xl + (size_t)s * 256 + lane * 4);
  float4 b = ld_half4(xr + (size_t)d * 256 + lane * 4);
  float4 at = *reinterpret_cast<const float4*>(att + lane * 4);
  float p = 0.f, v;
  v = a.x + b.x; p += (v > 0.f ? v : 0.2f * v) * at.x;
  v = a.y + b.y; p += (v > 0.f ? v : 0.2f * v) * at.y;
  v = a.z + b.z; p += (v > 0.f ? v : 0.2f * v) * at.z;
  v = a.w + b.w; p += (v > 0.f ? v : 0.2f * v) * at.w;
  p += __shfl_xor(p, 1, 64);
  p += __shfl_xor(p, 2, 64);
  p += __shfl_xor(p, 4, 64);
  p += __shfl_xor(p, 8, 64);
  if ((lane & 15) == 0) {
    int h = lane >> 4;
    score[(size_t)e * 4 + h] = p;
    atomicMax(&smax_i[d * 4 + h], f2ord(p));
  }
}

// pass B: ex = exp(score - max); den += ex   (score overwritten with ex)
__global__ void k_gat_expsum(const int* __restrict__ dst, const int* __restrict__ smax_i,
                             float* __restrict__ score, float* __restrict__ den) {
  int t = blockIdx.x * 256 + threadIdx.x;
  if (t >= (N_EDGES + N_NODES) * 4) return;
  int e = t >> 2, h = t & 3;
  int d = (e < N_EDGES) ? dst[e] : (e - N_EDGES);
  float ex = __expf(score[t] - ord2f(smax_i[d * 4 + h]));
  score[t] = ex;
  atomAdd(&den[d * 4 + h], ex);
}

// pass C: gat_acc[d][c] += 0.25 * sum_h alpha[h]*xl[s][h*64+c]
__global__ __launch_bounds__(256) void k_gat_aggr(
    const __half* __restrict__ xl, const int* __restrict__ src, const int* __restrict__ dst,
    const float* __restrict__ score, const float* __restrict__ den,
    float* __restrict__ gat_acc) {
  int e = blockIdx.x * 4 + (threadIdx.x >> 6);
  if (e >= N_EDGES + N_NODES) return;
  int lane = threadIdx.x & 63;
  int s, d;
  if (e < N_EDGES) { s = src[e]; d = dst[e]; } else { s = e - N_EDGES; d = s; }
  int h = lane >> 4;
  float alpha = score[(size_t)e * 4 + h] / den[d * 4 + h];
  float4 v = ld_half4(xl + (size_t)s * 256 + lane * 4);
  v.x *= alpha; v.y *= alpha; v.z *= alpha; v.w *= alpha;
  v.x += __shfl_xor(v.x, 16, 64); v.y += __shfl_xor(v.y, 16, 64);
  v.z += __shfl_xor(v.z, 16, 64); v.w += __shfl_xor(v.w, 16, 64);
  v.x += __shfl_xor(v.x, 32, 64); v.y += __shfl_xor(v.y, 32, 64);
  v.z += __shfl_xor(v.z, 32, 64); v.w += __shfl_xor(v.w, 32, 64);
  if (lane < 16) {
    float* p = gat_acc + (size_t)d * HID + lane * 4;
    atomAdd(p + 0, 0.25f * v.x);
    atomAdd(p + 1, 0.25f * v.y);
    atomAdd(p + 2, 0.25f * v.z);
    atomAdd(p + 3, 0.25f * v.w);
  }
}

// ---------------- SAGE ----------------
__global__ void k_sage_init(float* __restrict__ nsum, float* __restrict__ cnt) {
  int idx = blockIdx.x * 256 + threadIdx.x;  // N*64 exact
  nsum[idx] = 0.f;
  if ((idx & 63) == 0) cnt[idx >> 6] = 0.f;
}
__global__ void k_sage_scatter(const int* __restrict__ src, const int* __restrict__ dst,
                               const float* __restrict__ h2, float* __restrict__ nsum,
                               float* __restrict__ cnt) {
  int idx = blockIdx.x * 256 + threadIdx.x;
  int e = idx >> 4, q = idx & 15;
  if (e >= N_EDGES) return;
  int s = src[e], d = dst[e];
  float4 v = reinterpret_cast<const float4*>(h2 + (size_t)s * HID)[q];
  float* p = nsum + (size_t)d * HID + q * 4;
  atomAdd(p + 0, v.x);
  atomAdd(p + 1, v.y);
  atomAdd(p + 2, v.z);
  atomAdd(p + 3, v.w);
  if (q == 0) atomAdd(&cnt[d], 1.0f);
}
// sage_out = nmean@Wl + h2@Wr (bias added in LN kernel)
__global__ __launch_bounds__(256) void k_sage_gemm(
    const float* __restrict__ nsum, const float* __restrict__ cnt,
    const float* __restrict__ h2, const float* __restrict__ Wl,
    const float* __restrict__ Wr, float* __restrict__ out) {
  int f = threadIdx.x & 63;
  int jg = threadIdx.x >> 6;
  int n0 = blockIdx.x * 8 + jg * 2;
  float inv0 = 1.f / fmaxf(cnt[n0], 1.f);
  float inv1 = 1.f / fmaxf(cnt[n0 + 1], 1.f);
  float a0 = 0.f, a1 = 0.f;
  for (int k = 0; k < HID; ++k) {
    float wl = Wl[k * HID + f], wr = Wr[k * HID + f];
    a0 += nsum[(size_t)n0 * HID + k] * inv0 * wl + h2[(size_t)n0 * HID + k] * wr;
    a1 += nsum[(size_t)(n0 + 1) * HID + k] * inv1 * wl + h2[(size_t)(n0 + 1) * HID + k] * wr;
  }
  out[(size_t)n0 * HID + f] = a0;
  out[(size_t)(n0 + 1) * HID + f] = a1;
}

// ---------------- heads ----------------
// node_mask arrives as int32 per harness convention ("integer -> const int*").
__global__ __launch_bounds__(256) void k_heads(
    const float* __restrict__ h_init, const float* __restrict__ h2,
    const float* __restrict__ h3, const int* __restrict__ mask,
    const float* __restrict__ mort_W, const float* __restrict__ mort_b,
    const float* __restrict__ hours_W, const float* __restrict__ hours_b,
    const float* __restrict__ disc_W, const float* __restrict__ disc_b,
    float* __restrict__ out) {
  int n = blockIdx.x * 4 + (threadIdx.x >> 6);
  int lane = threadIdx.x & 63;
  float m = (mask[n] != 0) ? 1.f : 0.f;
  size_t base = (size_t)n * HID;
  float v0 = h_init[base + lane] * m;
  float v1 = h2[base + lane] * m;
  float v2 = h3[base + lane] * m;
  float pm = v0 * mort_W[lane] + v1 * mort_W[64 + lane] + v2 * mort_W[128 + lane];
  float ph = v0 * hours_W[lane] + v1 * hours_W[64 + lane] + v2 * hours_W[128 + lane];
  float d0 = v0 * disc_W[lane * 4 + 0] + v1 * disc_W[(64 + lane) * 4 + 0] + v2 * disc_W[(128 + lane) * 4 + 0];
  float d1 = v0 * disc_W[lane * 4 + 1] + v1 * disc_W[(64 + lane) * 4 + 1] + v2 * disc_W[(128 + lane) * 4 + 1];
  float d2 = v0 * disc_W[lane * 4 + 2] + v1 * disc_W[(64 + lane) * 4 + 2] + v2 * disc_W[(128 + lane) * 4 + 2];
  float d3 = v0 * disc_W[lane * 4 + 3] + v1 * disc_W[(64 + lane) * 4 + 3] + v2 * disc_W[(128 + lane) * 4 + 3];
  pm = wsum(pm); ph = wsum(ph);
  d0 = wsum(d0); d1 = wsum(d1); d2 = wsum(d2); d3 = wsum(d3);
  if (lane == 0) {
    out[n] = pm + mort_b[0];
    out[N_NODES + n] = ph + hours_b[0];
    float* dd = out + 2 * N_NODES + (size_t)n * 4;
    dd[0] = d0 + disc_b[0];
    dd[1] = d1 + disc_b[1];
    dd[2] = d2 + disc_b[2];
    dd[3] = d3 + disc_b[3];
  }
}

extern "C" void kernel_launch(void* const* d_in, const int* in_sizes, int n_in,
                              void* d_out, int out_size, void* d_ws, size_t ws_size,
                              hipStream_t stream) {
  const float* x       = (const float*)d_in[0];
  const int*   ei      = (const int*)d_in[1];
  const float* ew      = (const float*)d_in[2];
  const int*   mask    = (const int*)d_in[3];
  const float* gcn_W   = (const float*)d_in[4];
  const float* gcn_b   = (const float*)d_in[5];
  const float* proj_W  = (const float*)d_in[6];
  const float* proj_b  = (const float*)d_in[7];
  const float* ln1_g   = (const float*)d_in[8];
  const float* ln1_b   = (const float*)d_in[9];
  const float* gat_Wl  = (const float*)d_in[10];
  const float* gat_Wr  = (const float*)d_in[11];
  const float* gat_att = (const float*)d_in[12];
  const float* gat_b   = (const float*)d_in[13];
  const float* ln2_g   = (const float*)d_in[14];
  const float* ln2_b   = (const float*)d_in[15];
  const float* sage_Wl = (const float*)d_in[16];
  const float* sage_bl = (const float*)d_in[17];
  const float* sage_Wr = (const float*)d_in[18];
  const float* ln3_g   = (const float*)d_in[19];
  const float* ln3_b   = (const float*)d_in[20];
  // d_in[21..24]: edge-MLP params — output unused by the reference; skipped.
  const float* mort_W  = (const float*)d_in[25];
  const float* mort_b  = (const float*)d_in[26];
  const float* hours_W = (const float*)d_in[27];
  const float* hours_b = (const float*)d_in[28];
  const float* disc_W  = (const float*)d_in[29];
  const float* disc_b  = (const float*)d_in[30];

  const int* src = ei;
  const int* dst = ei + N_EDGES;
  float* out = (float*)d_out;

  // ---- compact workspace layout: ~50.3M floats ≈ 201 MB ----
  float* ws = (float*)d_ws;
  const size_t F = (size_t)N_NODES * HID;  // 6.4M
  float* h_init = ws;
  float* h2     = ws + 1 * F;
  float* h3     = ws + 2 * F;
  float* xw     = ws + 3 * F;            // fp32, GCN phase only
  __half* xl    = (__half*)(ws + 3 * F); // fp16, GAT phase
  __half* xr    = (__half*)(ws + 5 * F);
  float* nsum   = ws + 3 * F;            // fp32, SAGE phase (xl dead)
  float* sage_o = ws + 5 * F;            // fp32, SAGE phase (xr dead)
  float* score  = ws + 7 * F;            // (E+N)*4
  size_t off = 7 * F + (size_t)(N_EDGES + N_NODES) * 4;
  float* den  = ws + off; off += (size_t)N_NODES * 4;
  float* deg  = ws + off; off += N_NODES;
  float* dinv = ws + off; off += N_NODES;
  float* cnt  = ws + off; off += N_NODES;
  int* smax_i = (int*)(ws + off);

  const int EN = N_EDGES + N_NODES;

  // --- GCN layer ---
  k_in_gemm<<<N_NODES / 8, 128, 0, stream>>>(x, gcn_W, proj_W, proj_b, xw, h2);
  k_deg_init<<<(N_NODES + 255) / 256, 256, 0, stream>>>(deg);
  k_deg_scatter<<<(N_EDGES + 255) / 256, 256, 0, stream>>>(dst, ew, deg);
  k_gcn_self<<<(N_NODES * HID) / 256, 256, 0, stream>>>(deg, xw, dinv, h3);
  k_gcn_scatter<<<(N_EDGES * 16) / 256, 256, 0, stream>>>(src, dst, ew, dinv, xw, h3);
  k_ln_relu_add<<<N_NODES / 4, 256, 0, stream>>>(h3, gcn_b, ln1_g, ln1_b, h2, h_init);

  // --- GATv2 layer ---  (gat_acc lives in the h3 slot)
  k_gat_gemm<<<N_NODES / 8, 512, 0, stream>>>(h_init, gat_Wl, gat_Wr, xl, xr);
  k_gat_init<<<(N_NODES * HID) / 256, 256, 0, stream>>>(h3, smax_i, den);
  k_gat_score<<<EN / 4, 256, 0, stream>>>(xl, xr, src, dst, gat_att, score, smax_i);
  k_gat_expsum<<<(EN * 4 + 255) / 256, 256, 0, stream>>>(dst, smax_i, score, den);
  k_gat_aggr<<<EN / 4, 256, 0, stream>>>(xl, src, dst, score, den, h3);
  k_ln_relu_add<<<N_NODES / 4, 256, 0, stream>>>(h3, gat_b, ln2_g, ln2_b, h_init, h2);

  // --- SAGE layer ---
  k_sage_init<<<(N_NODES * HID) / 256, 256, 0, stream>>>(nsum, cnt);
  k_sage_scatter<<<(N_EDGES * 16) / 256, 256, 0, stream>>>(src, dst, h2, nsum, cnt);
  k_sage_gemm<<<N_NODES / 8, 256, 0, stream>>>(nsum, cnt, h2, sage_Wl, sage_Wr, sage_o);
  k_ln_relu_add<<<N_NODES / 4, 256, 0, stream>>>(sage_o, sage_bl, ln3_g, ln3_b, h2, h3);

  // --- heads ---
  k_heads<<<N_NODES / 4, 256, 0, stream>>>(h_init, h2, h3, mask, mort_W, mort_b,
                                           hours_W, hours_b, disc_W, disc_b, out);
}

// Round 4
// 973.464 us; speedup vs baseline: 3.7828x; 3.7828x over previous
//
#include <hip/hip_runtime.h>
#include <hip/hip_fp16.h>
#include <math.h>

#define N_NODES 100000
#define N_EDGES 1000000
#define F_IN    128
#define HID     64
#define HEADS   4
#define NCLS    4
#define SCAN_BLK 98   // ceil(N_NODES / 1024)

// ---------------- helpers ----------------
__device__ __forceinline__ float wsum(float v) {
#pragma unroll
  for (int o = 32; o > 0; o >>= 1) v += __shfl_xor(v, o, 64);
  return v;
}
struct Half4 { __half2 a, b; };
__device__ __forceinline__ float4 ld_half4(const __half* p) {
  Half4 h = *reinterpret_cast<const Half4*>(p);
  float2 f0 = __half22float2(h.a), f1 = __half22float2(h.b);
  return make_float4(f0.x, f0.y, f1.x, f1.y);
}

// ---------------- CSR build (by dst) ----------------
__global__ void k_zero_cnt(int* __restrict__ cnt) {
  int i = blockIdx.x * 256 + threadIdx.x;
  if (i < N_NODES) cnt[i] = 0;
}
__global__ void k_hist(const int* __restrict__ dst, int* __restrict__ cnt) {
  int e = blockIdx.x * 256 + threadIdx.x;
  if (e < N_EDGES) atomicAdd(&cnt[dst[e]], 1);
}
// block-level scan: 1024 elements/block (256 thr x 4)
__global__ __launch_bounds__(256) void k_scan1(const int* __restrict__ cnt,
                                               int* __restrict__ partial,
                                               int* __restrict__ bsum) {
  __shared__ int lds[256];
  int t = threadIdx.x;
  int base = blockIdx.x * 1024 + t * 4;
  int v0 = (base + 0 < N_NODES) ? cnt[base + 0] : 0;
  int v1 = (base + 1 < N_NODES) ? cnt[base + 1] : 0;
  int v2 = (base + 2 < N_NODES) ? cnt[base + 2] : 0;
  int v3 = (base + 3 < N_NODES) ? cnt[base + 3] : 0;
  int s = v0 + v1 + v2 + v3;
  lds[t] = s;
  __syncthreads();
  for (int o = 1; o < 256; o <<= 1) {
    int x = (t >= o) ? lds[t - o] : 0;
    __syncthreads();
    lds[t] += x;
    __syncthreads();
  }
  int excl = lds[t] - s;
  if (base + 0 < N_NODES) partial[base + 0] = excl;
  if (base + 1 < N_NODES) partial[base + 1] = excl + v0;
  if (base + 2 < N_NODES) partial[base + 2] = excl + v0 + v1;
  if (base + 3 < N_NODES) partial[base + 3] = excl + v0 + v1 + v2;
  if (t == 255) bsum[blockIdx.x] = lds[255];
}
__global__ void k_scan2(int* __restrict__ bsum) {  // 1 block, 128 threads
  __shared__ int lds[128];
  int t = threadIdx.x;
  int v = (t < SCAN_BLK) ? bsum[t] : 0;
  lds[t] = v;
  __syncthreads();
  for (int o = 1; o < 128; o <<= 1) {
    int x = (t >= o) ? lds[t - o] : 0;
    __syncthreads();
    lds[t] += x;
    __syncthreads();
  }
  if (t < SCAN_BLK) bsum[t] = lds[t] - v;  // exclusive
}
__global__ void k_scan3(const int* __restrict__ partial, const int* __restrict__ bsum,
                        int* __restrict__ row_ptr, int* __restrict__ cursor) {
  int i = blockIdx.x * 256 + threadIdx.x;
  if (i < N_NODES) {
    int v = partial[i] + bsum[i >> 10];
    row_ptr[i] = v;
    cursor[i] = v;
  }
  if (i == 0) row_ptr[N_NODES] = N_EDGES;
}
__global__ void k_fill(const int* __restrict__ src, const int* __restrict__ dst,
                       const float* __restrict__ ew, int* __restrict__ cursor,
                       int* __restrict__ csr_src, float* __restrict__ csr_w) {
  int e = blockIdx.x * 256 + threadIdx.x;
  if (e >= N_EDGES) return;
  int d = dst[e];
  int p = atomicAdd(&cursor[d], 1);
  csr_src[p] = src[e];
  csr_w[p] = ew[e];
}

// ---------------- dense: xw16 = half(x@gcn_W) ; xp = x@proj_W + proj_b ----------
__global__ __launch_bounds__(128) void k_in_gemm(
    const float* __restrict__ x, const float* __restrict__ gcn_W,
    const float* __restrict__ proj_W, const float* __restrict__ proj_b,
    __half* __restrict__ xw16, float* __restrict__ xp) {
  int f = threadIdx.x & 63;
  bool is_proj = threadIdx.x >= 64;
  const float* W = is_proj ? proj_W : gcn_W;
  int n0 = blockIdx.x * 8;
  float acc[8] = {0.f,0.f,0.f,0.f,0.f,0.f,0.f,0.f};
  for (int k = 0; k < F_IN; ++k) {
    float w = W[k * HID + f];
#pragma unroll
    for (int j = 0; j < 8; ++j) acc[j] += x[(size_t)(n0 + j) * F_IN + k] * w;
  }
  if (is_proj) {
    float b = proj_b[f];
#pragma unroll
    for (int j = 0; j < 8; ++j) xp[(size_t)(n0 + j) * HID + f] = acc[j] + b;
  } else {
#pragma unroll
    for (int j = 0; j < 8; ++j) xw16[(size_t)(n0 + j) * HID + f] = __float2half(acc[j]);
  }
}

// ---------------- GCN: deg/dinv from CSR (no atomics) ----------------
__global__ void k_deg(const int* __restrict__ row_ptr, const float* __restrict__ csr_w,
                      float* __restrict__ dinv) {
  int n = blockIdx.x * 256 + threadIdx.x;
  if (n >= N_NODES) return;
  float deg = 1.0f;  // self-loop weight
  int end = row_ptr[n + 1];
  for (int i = row_ptr[n]; i < end; ++i) deg += csr_w[i];
  dinv[n] = rsqrtf(deg);  // deg >= 1 always
}

// pull-gather + LN + relu + residual, one wave per node
__global__ __launch_bounds__(256) void k_gcn_fused(
    const int* __restrict__ row_ptr, const int* __restrict__ csr_src,
    const float* __restrict__ csr_w, const float* __restrict__ dinv,
    const __half* __restrict__ xw16, const float* __restrict__ xp,
    const float* __restrict__ gcn_b, const float* __restrict__ g,
    const float* __restrict__ bb, float* __restrict__ h_init) {
  int n = blockIdx.x * 4 + (threadIdx.x >> 6);
  int lane = threadIdx.x & 63;
  float di = dinv[n];
  float acc = di * di * __half2float(xw16[(size_t)n * HID + lane]);  // self loop
  int beg = row_ptr[n], end = row_ptr[n + 1];
  for (int i = beg; i < end; ++i) {
    int s = csr_src[i];
    float nrm = dinv[s] * csr_w[i] * di;
    acc += nrm * __half2float(xw16[(size_t)s * HID + lane]);
  }
  float v = acc + gcn_b[lane];
  float mu = wsum(v) * (1.f / HID);
  float dv = v - mu;
  float var = wsum(dv * dv) * (1.f / HID);
  float h = dv * rsqrtf(var + 1e-5f) * g[lane] + bb[lane];
  h = h > 0.f ? h : 0.f;
  h_init[(size_t)n * HID + lane] = h + xp[(size_t)n * HID + lane];
}

// ---------------- GATv2 linear: xl = h@Wl, xr = h@Wr (fp16 out, each [N,256]) ----
__global__ __launch_bounds__(512) void k_gat_gemm(
    const float* __restrict__ h, const float* __restrict__ Wl,
    const float* __restrict__ Wr, __half* __restrict__ xl, __half* __restrict__ xr) {
  int f = threadIdx.x & 255;
  bool right = threadIdx.x >= 256;
  const float* W = right ? Wr : Wl;
  __half* out = right ? xr : xl;
  int n0 = blockIdx.x * 8;
  float acc[8] = {0.f,0.f,0.f,0.f,0.f,0.f,0.f,0.f};
  for (int k = 0; k < HID; ++k) {
    float w = W[k * 256 + f];
#pragma unroll
    for (int j = 0; j < 8; ++j) acc[j] += h[(size_t)(n0 + j) * HID + k] * w;
  }
#pragma unroll
  for (int j = 0; j < 8; ++j) out[(size_t)(n0 + j) * 256 + f] = __float2half(acc[j]);
}

// ---------------- GATv2 fused: online softmax + aggregate + head-mean + LN ------
// One wave per dst node. Lane holds feats 4*lane..4*lane+3 of [H*C]=256; head = lane>>4.
__global__ __launch_bounds__(256) void k_gat_fused(
    const int* __restrict__ row_ptr, const int* __restrict__ csr_src,
    const __half* __restrict__ xl, const __half* __restrict__ xr,
    const float* __restrict__ att, const float* __restrict__ gat_b,
    const float* __restrict__ g, const float* __restrict__ bb,
    const float* __restrict__ h_init, float* __restrict__ h2,
    __half* __restrict__ h2_16) {
  int n = blockIdx.x * 4 + (threadIdx.x >> 6);
  int lane = threadIdx.x & 63;
  float4 xrv = ld_half4(xr + (size_t)n * 256 + lane * 4);
  float4 atv = *reinterpret_cast<const float4*>(att + lane * 4);
  float4 xlv = ld_half4(xl + (size_t)n * 256 + lane * 4);
  // self-loop score (per-head dot across 16-lane group)
  float p, v;
  v = xlv.x + xrv.x; p  = (v > 0.f ? v : 0.2f * v) * atv.x;
  v = xlv.y + xrv.y; p += (v > 0.f ? v : 0.2f * v) * atv.y;
  v = xlv.z + xrv.z; p += (v > 0.f ? v : 0.2f * v) * atv.z;
  v = xlv.w + xrv.w; p += (v > 0.f ? v : 0.2f * v) * atv.w;
  p += __shfl_xor(p, 1); p += __shfl_xor(p, 2);
  p += __shfl_xor(p, 4); p += __shfl_xor(p, 8);
  float m = p, den = 1.f;    // softmax init with self-loop: exp(p-p)=1
  float4 acc = xlv;
  int beg = row_ptr[n], end = row_ptr[n + 1];
  for (int i = beg; i < end; ++i) {
    int s = csr_src[i];
    float4 a = ld_half4(xl + (size_t)s * 256 + lane * 4);
    float q;
    v = a.x + xrv.x; q  = (v > 0.f ? v : 0.2f * v) * atv.x;
    v = a.y + xrv.y; q += (v > 0.f ? v : 0.2f * v) * atv.y;
    v = a.z + xrv.z; q += (v > 0.f ? v : 0.2f * v) * atv.z;
    v = a.w + xrv.w; q += (v > 0.f ? v : 0.2f * v) * atv.w;
    q += __shfl_xor(q, 1); q += __shfl_xor(q, 2);
    q += __shfl_xor(q, 4); q += __shfl_xor(q, 8);
    float mn = fmaxf(m, q);
    float sc = __expf(m - mn), w = __expf(q - mn);
    den = den * sc + w;
    acc.x = acc.x * sc + w * a.x;
    acc.y = acc.y * sc + w * a.y;
    acc.z = acc.z * sc + w * a.z;
    acc.w = acc.w * sc + w * a.w;
    m = mn;
  }
  float inv = 1.f / den;
  acc.x *= inv; acc.y *= inv; acc.z *= inv; acc.w *= inv;
  // mean over heads: lanes l, l^16, l^32, l^48 hold same feature of different heads
  acc.x += __shfl_xor(acc.x, 16); acc.y += __shfl_xor(acc.y, 16);
  acc.z += __shfl_xor(acc.z, 16); acc.w += __shfl_xor(acc.w, 16);
  acc.x += __shfl_xor(acc.x, 32); acc.y += __shfl_xor(acc.y, 32);
  acc.z += __shfl_xor(acc.z, 32); acc.w += __shfl_xor(acc.w, 32);
  // redistribute: feature `lane` = component (lane&3) of lane (lane>>2)
  int srcl = lane >> 2;
  float t0 = __shfl(acc.x, srcl), t1 = __shfl(acc.y, srcl);
  float t2 = __shfl(acc.z, srcl), t3 = __shfl(acc.w, srcl);
  int r = lane & 3;
  float mean = (r == 0) ? t0 : (r == 1) ? t1 : (r == 2) ? t2 : t3;
  float val = mean * 0.25f + gat_b[lane];
  float mu = wsum(val) * (1.f / HID);
  float dv = val - mu;
  float var = wsum(dv * dv) * (1.f / HID);
  float h = dv * rsqrtf(var + 1e-5f) * g[lane] + bb[lane];
  h = h > 0.f ? h : 0.f;
  float outv = h + h_init[(size_t)n * HID + lane];
  h2[(size_t)n * HID + lane] = outv;
  h2_16[(size_t)n * HID + lane] = __float2half(outv);
}

// ---------------- SAGE fused: mean-gather + 2 matvecs (shfl bcast) + LN --------
__global__ __launch_bounds__(256) void k_sage_fused(
    const int* __restrict__ row_ptr, const int* __restrict__ csr_src,
    const __half* __restrict__ h2_16, const float* __restrict__ h2,
    const float* __restrict__ Wl, const float* __restrict__ Wr,
    const float* __restrict__ sage_bl, const float* __restrict__ g,
    const float* __restrict__ bb, float* __restrict__ h3) {
  int n = blockIdx.x * 4 + (threadIdx.x >> 6);
  int lane = threadIdx.x & 63;
  int beg = row_ptr[n], end = row_ptr[n + 1];
  float sum = 0.f;
  for (int i = beg; i < end; ++i) {
    int s = csr_src[i];
    sum += __half2float(h2_16[(size_t)s * HID + lane]);
  }
  float nmean = sum / fmaxf((float)(end - beg), 1.f);
  float hv = h2[(size_t)n * HID + lane];
  float acc = 0.f;
  for (int k = 0; k < HID; ++k) {
    float nk = __shfl(nmean, k);
    float hk = __shfl(hv, k);
    acc += nk * Wl[k * HID + lane] + hk * Wr[k * HID + lane];
  }
  float v = acc + sage_bl[lane];
  float mu = wsum(v) * (1.f / HID);
  float dv = v - mu;
  float var = wsum(dv * dv) * (1.f / HID);
  float h = dv * rsqrtf(var + 1e-5f) * g[lane] + bb[lane];
  h = h > 0.f ? h : 0.f;
  h3[(size_t)n * HID + lane] = h + hv;
}

// ---------------- heads ----------------
__global__ __launch_bounds__(256) void k_heads(
    const float* __restrict__ h_init, const float* __restrict__ h2,
    const float* __restrict__ h3, const int* __restrict__ mask,
    const float* __restrict__ mort_W, const float* __restrict__ mort_b,
    const float* __restrict__ hours_W, const float* __restrict__ hours_b,
    const float* __restrict__ disc_W, const float* __restrict__ disc_b,
    float* __restrict__ out) {
  int n = blockIdx.x * 4 + (threadIdx.x >> 6);
  int lane = threadIdx.x & 63;
  float m = (mask[n] != 0) ? 1.f : 0.f;
  size_t base = (size_t)n * HID;
  float v0 = h_init[base + lane] * m;
  float v1 = h2[base + lane] * m;
  float v2 = h3[base + lane] * m;
  float pm = v0 * mort_W[lane] + v1 * mort_W[64 + lane] + v2 * mort_W[128 + lane];
  float ph = v0 * hours_W[lane] + v1 * hours_W[64 + lane] + v2 * hours_W[128 + lane];
  float d0 = v0 * disc_W[lane * 4 + 0] + v1 * disc_W[(64 + lane) * 4 + 0] + v2 * disc_W[(128 + lane) * 4 + 0];
  float d1 = v0 * disc_W[lane * 4 + 1] + v1 * disc_W[(64 + lane) * 4 + 1] + v2 * disc_W[(128 + lane) * 4 + 1];
  float d2 = v0 * disc_W[lane * 4 + 2] + v1 * disc_W[(64 + lane) * 4 + 2] + v2 * disc_W[(128 + lane) * 4 + 2];
  float d3 = v0 * disc_W[lane * 4 + 3] + v1 * disc_W[(64 + lane) * 4 + 3] + v2 * disc_W[(128 + lane) * 4 + 3];
  pm = wsum(pm); ph = wsum(ph);
  d0 = wsum(d0); d1 = wsum(d1); d2 = wsum(d2); d3 = wsum(d3);
  if (lane == 0) {
    out[n] = pm + mort_b[0];
    out[N_NODES + n] = ph + hours_b[0];
    float* dd = out + 2 * N_NODES + (size_t)n * 4;
    dd[0] = d0 + disc_b[0];
    dd[1] = d1 + disc_b[1];
    dd[2] = d2 + disc_b[2];
    dd[3] = d3 + disc_b[3];
  }
}

extern "C" void kernel_launch(void* const* d_in, const int* in_sizes, int n_in,
                              void* d_out, int out_size, void* d_ws, size_t ws_size,
                              hipStream_t stream) {
  const float* x       = (const float*)d_in[0];
  const int*   ei      = (const int*)d_in[1];
  const float* ew      = (const float*)d_in[2];
  const int*   mask    = (const int*)d_in[3];
  const float* gcn_W   = (const float*)d_in[4];
  const float* gcn_b   = (const float*)d_in[5];
  const float* proj_W  = (const float*)d_in[6];
  const float* proj_b  = (const float*)d_in[7];
  const float* ln1_g   = (const float*)d_in[8];
  const float* ln1_b   = (const float*)d_in[9];
  const float* gat_Wl  = (const float*)d_in[10];
  const float* gat_Wr  = (const float*)d_in[11];
  const float* gat_att = (const float*)d_in[12];
  const float* gat_b   = (const float*)d_in[13];
  const float* ln2_g   = (const float*)d_in[14];
  const float* ln2_b   = (const float*)d_in[15];
  const float* sage_Wl = (const float*)d_in[16];
  const float* sage_bl = (const float*)d_in[17];
  const float* sage_Wr = (const float*)d_in[18];
  const float* ln3_g   = (const float*)d_in[19];
  const float* ln3_b   = (const float*)d_in[20];
  // d_in[21..24]: edge-MLP params — output unused by the reference; skipped.
  const float* mort_W  = (const float*)d_in[25];
  const float* mort_b  = (const float*)d_in[26];
  const float* hours_W = (const float*)d_in[27];
  const float* hours_b = (const float*)d_in[28];
  const float* disc_W  = (const float*)d_in[29];
  const float* disc_b  = (const float*)d_in[30];

  const int* src = ei;
  const int* dst = ei + N_EDGES;
  float* out = (float*)d_out;

  // ---- workspace layout (~49M floats = 196 MB) ----
  float* ws = (float*)d_ws;
  const size_t F = (size_t)N_NODES * HID;  // 6.4M floats
  float* h_init = ws;
  float* h2     = ws + 1 * F;
  float* h3     = ws + 2 * F;
  float* xp     = h3;                              // fp32, dead before h3 written
  __half* xl    = (__half*)(ws + 3 * F);           // N*256 halfs
  __half* xw16  = xl;                              // N*64 halfs, dead before xl written
  __half* xr    = (__half*)(ws + 3 * F + (size_t)N_NODES * 128);
  __half* h2_16 = (__half*)(ws + 3 * F + (size_t)N_NODES * 256);
  float* tail   = ws + 3 * F + (size_t)N_NODES * 256 + (size_t)N_NODES * 32;
  int*   csr_src = (int*)tail;           tail += N_EDGES;
  float* csr_w   = tail;                 tail += N_EDGES;
  int*   row_ptr = (int*)tail;           tail += N_NODES + 64;
  int*   cursor  = (int*)tail;           tail += N_NODES;
  int*   cnt     = (int*)tail;           tail += N_NODES;
  int*   partial = (int*)tail;           tail += N_NODES;
  int*   bsum    = (int*)tail;           tail += 128;
  float* dinv    = tail;

  const int GE = (N_EDGES + 255) / 256;
  const int GN = (N_NODES + 255) / 256;

  // --- CSR build (by dst) ---
  k_zero_cnt<<<GN, 256, 0, stream>>>(cnt);
  k_hist<<<GE, 256, 0, stream>>>(dst, cnt);
  k_scan1<<<SCAN_BLK, 256, 0, stream>>>(cnt, partial, bsum);
  k_scan2<<<1, 128, 0, stream>>>(bsum);
  k_scan3<<<GN, 256, 0, stream>>>(partial, bsum, row_ptr, cursor);
  k_fill<<<GE, 256, 0, stream>>>(src, dst, ew, cursor, csr_src, csr_w);

  // --- GCN layer ---
  k_in_gemm<<<N_NODES / 8, 128, 0, stream>>>(x, gcn_W, proj_W, proj_b, xw16, xp);
  k_deg<<<GN, 256, 0, stream>>>(row_ptr, csr_w, dinv);
  k_gcn_fused<<<N_NODES / 4, 256, 0, stream>>>(row_ptr, csr_src, csr_w, dinv, xw16,
                                               xp, gcn_b, ln1_g, ln1_b, h_init);

  // --- GATv2 layer ---
  k_gat_gemm<<<N_NODES / 8, 512, 0, stream>>>(h_init, gat_Wl, gat_Wr, xl, xr);
  k_gat_fused<<<N_NODES / 4, 256, 0, stream>>>(row_ptr, csr_src, xl, xr, gat_att,
                                               gat_b, ln2_g, ln2_b, h_init, h2, h2_16);

  // --- SAGE layer ---
  k_sage_fused<<<N_NODES / 4, 256, 0, stream>>>(row_ptr, csr_src, h2_16, h2, sage_Wl,
                                                sage_Wr, sage_bl, ln3_g, ln3_b, h3);

  // --- heads ---
  k_heads<<<N_NODES / 4, 256, 0, stream>>>(h_init, h2, h3, mask, mort_W, mort_b,
                                           hours_W, hours_b, disc_W, disc_b, out);
}